// Round 8
// baseline (65.896 us; speedup 1.0000x reference)
//
#include <hip/hip_runtime.h>

#define NN 8192
#define GAMMA 0.1f

typedef float v2f __attribute__((ext_vector_type(2)));
typedef float v4f __attribute__((ext_vector_type(4)));

// CC = (GAMMA * log2(e))^2 ; CC256 = CC/256
#define CCONST 2.0813689894397856e-2f
#define CC256  8.130347615003068e-5f

// prep: 64 blocks x 256. One thread per row (x rows: gid<NN, y rows: gid>=NN).
// Gathers raw feat = [W[row.u], H[row.v]], wave-reduces min/max -> per-wave
// partials. Writes scaled raw vectors + (q,s) = (CC/256*||f||^2, CC/256*Σf):
//   x rows: ax = -f/8          (so dot(ax, ay) = -2*CC/256 * fx.fy)
//   y rows: ay = CC/16 * f
// The global-min/max-dependent correction is applied inside kexp via
// delta = cy - cx:  CC*d^2 = qy - 2d*sy + qx + 2d*sx + 16*CC256*d^2 + dot.
// x-rows also compute pred & w outputs.
__global__ __launch_bounds__(256) void prep_kernel(
    const int* __restrict__ x, const int* __restrict__ y,
    const float* __restrict__ W, const float* __restrict__ H,
    const float* __restrict__ nue, const float* __restrict__ nie,
    const float* __restrict__ l1w, const float* __restrict__ l1b,
    const float* __restrict__ l2w,
    const float* __restrict__ mfu, const float* __restrict__ mfi,
    float* __restrict__ pred, float* __restrict__ wout,
    float* __restrict__ pmn, float* __restrict__ pmx,
    float* __restrict__ fxs, float* __restrict__ fyn,
    float2* __restrict__ qsx, float2* __restrict__ qsy)
{
    int gid = blockIdx.x * 256 + threadIdx.x;
    bool isx = gid < NN;
    int i = isx ? gid : gid - NN;
    const int* idx = isx ? x : y;
    int iu = idx[2 * i], iv = idx[2 * i + 1];

    const float4* wp = (const float4*)(W + (size_t)iu * 8);
    float4 w0 = wp[0], w1 = wp[1];
    const float4* hp = (const float4*)(H + (size_t)iv * 8);
    float4 h0 = hp[0], h1 = hp[1];

    float f[16];
    f[0] = w0.x; f[1] = w0.y; f[2] = w0.z; f[3] = w0.w;
    f[4] = w1.x; f[5] = w1.y; f[6] = w1.z; f[7] = w1.w;
    f[8] = h0.x; f[9] = h0.y; f[10] = h0.z; f[11] = h0.w;
    f[12] = h1.x; f[13] = h1.y; f[14] = h1.z; f[15] = h1.w;

    float mn = f[0], mx = f[0];
    float q = 0.f, s = 0.f;
#pragma unroll
    for (int k = 0; k < 16; k++) {
        if (k) { mn = fminf(mn, f[k]); mx = fmaxf(mx, f[k]); }
        q = fmaf(f[k], f[k], q);
        s += f[k];
    }
#pragma unroll
    for (int off = 1; off < 64; off <<= 1) {
        mn = fminf(mn, __shfl_xor(mn, off));
        mx = fmaxf(mx, __shfl_xor(mx, off));
    }
    if ((threadIdx.x & 63) == 0) {
        int wid = gid >> 6;   // 0..255; waves 0..127 x-side, 128..255 y-side
        pmn[wid] = mn;
        pmx[wid] = mx;
    }

    // scaled raw vector + (q,s)
    float sc = isx ? (-1.f / 8.f) : (CCONST / 16.f);
    float o[16];
#pragma unroll
    for (int k = 0; k < 16; k++) o[k] = f[k] * sc;
    float4* dv = (float4*)((isx ? fxs : fyn) + (size_t)i * 16);
    dv[0] = make_float4(o[0], o[1], o[2], o[3]);
    dv[1] = make_float4(o[4], o[5], o[6], o[7]);
    dv[2] = make_float4(o[8], o[9], o[10], o[11]);
    dv[3] = make_float4(o[12], o[13], o[14], o[15]);
    (isx ? qsx : qsy)[i] = make_float2(q * CC256, s * CC256);

    if (isx) {
        // NCF MLP: z = [ncf_user_emb[u], ncf_item_emb[v]] (16)
        const float4* up = (const float4*)(nue + (size_t)iu * 8);
        float4 u0 = up[0], u1 = up[1];
        const float4* ip = (const float4*)(nie + (size_t)iv * 8);
        float4 i0 = ip[0], i1 = ip[1];
        float z[16];
        z[0] = u0.x; z[1] = u0.y; z[2] = u0.z; z[3] = u0.w;
        z[4] = u1.x; z[5] = u1.y; z[6] = u1.z; z[7] = u1.w;
        z[8] = i0.x; z[9] = i0.y; z[10] = i0.z; z[11] = i0.w;
        z[12] = i1.x; z[13] = i1.y; z[14] = i1.z; z[15] = i1.w;

        float p = 0.f;
#pragma unroll
        for (int k = 0; k < 8; k++) {
            float h = l1b[k];
#pragma unroll
            for (int m = 0; m < 16; m++) h = fmaf(z[m], l1w[k * 16 + m], h);
            h = fmaxf(h, 0.f);
            p = fmaf(h, l2w[k], p);
        }
        pred[i] = p;

        // MF dot: sum(mf_user_emb[u] * mf_item_emb[v])
        const float4* ap = (const float4*)(mfu + (size_t)iu * 8);
        float4 a0 = ap[0], a1 = ap[1];
        const float4* bp = (const float4*)(mfi + (size_t)iv * 8);
        float4 b0 = bp[0], b1 = bp[1];
        float wv = a0.x * b0.x + a0.y * b0.y + a0.z * b0.z + a0.w * b0.w
                 + a1.x * b1.x + a1.y * b1.y + a1.z * b1.z + a1.w * b1.w;
        wout[i] = wv;
    }
}

// Fused delta-reduce + kernel matrix.
// K[i][j] = exp2(-sqrt(max(nyc[i] + nxc[j] + dot(ay_i, ax_j), 0)))
//   nyc = qy - 2d*sy + 8*CC256*d^2 ; nxc = qx + 2d*sx + 8*CC256*d^2
//   d (delta) = cy - cx reduced from the 256 wave-partials per block.
// Block: 64 rows (ay via LDS) x 1024 cols (ax in regs, 4/thread), grid 8x128.
// K stores nontemporal: 268 MB streamed once, never re-read.
__global__ __launch_bounds__(256) void kexp_kernel(
    const float* __restrict__ fxs, const float* __restrict__ fyn,
    const float2* __restrict__ qsx, const float2* __restrict__ qsy,
    const float* __restrict__ pmn, const float* __restrict__ pmx,
    float* __restrict__ K)
{
    __shared__ float sfy[1024];
    __shared__ float sny[64];
    __shared__ float sred[4];
    int tid = threadIdx.x;
    int ib = blockIdx.y * 64;
    int jb = blockIdx.x * 1024;

    // phase 1: reduce partials; wave0:xmin wave1:xmax wave2:ymin wave3:ymax
    {
        int wv = tid >> 6, ln = tid & 63;
        const float* psrc = (wv & 1) ? pmx : pmn;
        int base = (wv >> 1) * 128;
        float u0 = psrc[base + ln], u1 = psrc[base + ln + 64];
        float v = (wv & 1) ? fmaxf(u0, u1) : fminf(u0, u1);
#pragma unroll
        for (int off = 1; off < 64; off <<= 1) {
            float o = __shfl_xor(v, off);
            v = (wv & 1) ? fmaxf(v, o) : fminf(v, o);
        }
        if (ln == 0) sred[wv] = v;
    }
    __syncthreads();
    float cx = sred[0] / (sred[1] - sred[0]);
    float cy = sred[2] / (sred[3] - sred[2]);
    float dl = cy - cx;
    float e8 = 8.f * CC256 * dl * dl;
    float dl2 = 2.f * dl;

    // phase 2: stage ay rows + corrected row norms
    for (int t = tid; t < 1024; t += 256) sfy[t] = fyn[(size_t)ib * 16 + t];
    if (tid < 64) {
        float2 qs = qsy[ib + tid];
        sny[tid] = qs.x - dl2 * qs.y + e8;
    }

    // phase 3: ax cols -> regs, corrected col norms
    int j0 = jb + tid * 4;
    v2f a[4][8];
    float nxr[4];
#pragma unroll
    for (int c2 = 0; c2 < 4; c2++) {
        const float4* p = (const float4*)(fxs + (size_t)(j0 + c2) * 16);
        float4 v0 = p[0], v1 = p[1], v2 = p[2], v3 = p[3];
        a[c2][0] = (v2f){v0.x, v0.y}; a[c2][1] = (v2f){v0.z, v0.w};
        a[c2][2] = (v2f){v1.x, v1.y}; a[c2][3] = (v2f){v1.z, v1.w};
        a[c2][4] = (v2f){v2.x, v2.y}; a[c2][5] = (v2f){v2.z, v2.w};
        a[c2][6] = (v2f){v3.x, v3.y}; a[c2][7] = (v2f){v3.z, v3.w};
        float2 qs = qsx[j0 + c2];
        nxr[c2] = qs.x + dl2 * qs.y + e8;
    }
    __syncthreads();

    const float4* sfy4 = (const float4*)sfy;

#pragma unroll 2
    for (int i = 0; i < 64; i++) {
        float4 q0 = sfy4[i * 4 + 0], q1 = sfy4[i * 4 + 1];
        float4 q2 = sfy4[i * 4 + 2], q3 = sfy4[i * 4 + 3];
        v2f fy[8];
        fy[0] = (v2f){q0.x, q0.y}; fy[1] = (v2f){q0.z, q0.w};
        fy[2] = (v2f){q1.x, q1.y}; fy[3] = (v2f){q1.z, q1.w};
        fy[4] = (v2f){q2.x, q2.y}; fy[5] = (v2f){q2.z, q2.w};
        fy[6] = (v2f){q3.x, q3.y}; fy[7] = (v2f){q3.z, q3.w};
        float nyv = sny[i];
        float r[4];
#pragma unroll
        for (int c2 = 0; c2 < 4; c2++) {
            v2f acc = (v2f){nyv, nxr[c2]};
#pragma unroll
            for (int k = 0; k < 8; k++)
                acc = __builtin_elementwise_fma(a[c2][k], fy[k], acc);
            float d2 = fmaxf(acc.x + acc.y, 0.f);
            r[c2] = __builtin_amdgcn_exp2f(-__builtin_amdgcn_sqrtf(d2));
        }
        v4f o = (v4f){r[0], r[1], r[2], r[3]};
        __builtin_nontemporal_store(o, (v4f*)(K + (size_t)(ib + i) * NN + j0));
    }
}

extern "C" void kernel_launch(void* const* d_in, const int* in_sizes, int n_in,
                              void* d_out, int out_size, void* d_ws, size_t ws_size,
                              hipStream_t stream) {
    const int* x = (const int*)d_in[0];
    const int* y = (const int*)d_in[1];
    const float* W = (const float*)d_in[2];
    const float* H = (const float*)d_in[3];
    const float* nue = (const float*)d_in[4];
    const float* nie = (const float*)d_in[5];
    const float* l1w = (const float*)d_in[6];
    const float* l1b = (const float*)d_in[7];
    const float* l2w = (const float*)d_in[8];
    const float* mfu = (const float*)d_in[9];
    const float* mfi = (const float*)d_in[10];

    float* out = (float*)d_out;
    float* K = out;
    float* pred = out + (size_t)NN * NN;
    float* wout = pred + NN;

    float* pmn  = (float*)d_ws;           // 256 wave-partial mins
    float* pmx  = pmn + 256;              // 256 wave-partial maxs
    float* fxs  = pmx + 256;              // 8192 x 16 scaled x vectors
    float* fyn  = fxs + (size_t)NN * 16;  // 8192 x 16 scaled y vectors
    float2* qsx = (float2*)(fyn + (size_t)NN * 16);  // (q,s) per x col
    float2* qsy = qsx + NN;                          // (q,s) per y row

    hipLaunchKernelGGL(prep_kernel, dim3(64), dim3(256), 0, stream,
                       x, y, W, H, nue, nie, l1w, l1b, l2w, mfu, mfi, pred, wout,
                       pmn, pmx, fxs, fyn, qsx, qsy);
    hipLaunchKernelGGL(kexp_kernel, dim3(8, 128), dim3(256), 0, stream,
                       fxs, fyn, qsx, qsy, pmn, pmx, K);
}

// Round 9
// 58.165 us; speedup vs baseline: 1.1329x; 1.1329x over previous
//
#include <hip/hip_runtime.h>

#define NN 8192
#define GAMMA 0.1f

typedef float v2f __attribute__((ext_vector_type(2)));
typedef float v4f __attribute__((ext_vector_type(4)));

// CC = (GAMMA * log2(e))^2 ; CC256 = CC/256
#define CCONST 2.0813689894397856e-2f
#define CC256  8.130347615003068e-5f

// prep: 64 blocks x 256. One thread per row (x rows: gid<NN, y rows: gid>=NN).
// Gathers raw feat = [W[row.u], H[row.v]], wave-reduces min/max -> per-wave
// partials. Writes scaled raw vectors + (q,s) = (CC/256*||f||^2, CC/256*Σf):
//   x rows: ax = -f/8          (so dot(ax, ay) = -2*CC/256 * fx.fy)
//   y rows: ay = CC/16 * f
// Global-min/max correction is applied inside kexp via delta = cy - cx:
//   CC*d^2 = qy - 2d*sy + qx + 2d*sx + 16*CC256*d^2 + dot.
// x-rows also compute pred & w outputs.
__global__ __launch_bounds__(256) void prep_kernel(
    const int* __restrict__ x, const int* __restrict__ y,
    const float* __restrict__ W, const float* __restrict__ H,
    const float* __restrict__ nue, const float* __restrict__ nie,
    const float* __restrict__ l1w, const float* __restrict__ l1b,
    const float* __restrict__ l2w,
    const float* __restrict__ mfu, const float* __restrict__ mfi,
    float* __restrict__ pred, float* __restrict__ wout,
    float* __restrict__ pmn, float* __restrict__ pmx,
    float* __restrict__ fxs, float* __restrict__ fyn,
    float2* __restrict__ qsx, float2* __restrict__ qsy)
{
    int gid = blockIdx.x * 256 + threadIdx.x;
    bool isx = gid < NN;
    int i = isx ? gid : gid - NN;
    const int* idx = isx ? x : y;
    int iu = idx[2 * i], iv = idx[2 * i + 1];

    const float4* wp = (const float4*)(W + (size_t)iu * 8);
    float4 w0 = wp[0], w1 = wp[1];
    const float4* hp = (const float4*)(H + (size_t)iv * 8);
    float4 h0 = hp[0], h1 = hp[1];

    float f[16];
    f[0] = w0.x; f[1] = w0.y; f[2] = w0.z; f[3] = w0.w;
    f[4] = w1.x; f[5] = w1.y; f[6] = w1.z; f[7] = w1.w;
    f[8] = h0.x; f[9] = h0.y; f[10] = h0.z; f[11] = h0.w;
    f[12] = h1.x; f[13] = h1.y; f[14] = h1.z; f[15] = h1.w;

    float mn = f[0], mx = f[0];
    float q = 0.f, s = 0.f;
#pragma unroll
    for (int k = 0; k < 16; k++) {
        if (k) { mn = fminf(mn, f[k]); mx = fmaxf(mx, f[k]); }
        q = fmaf(f[k], f[k], q);
        s += f[k];
    }
#pragma unroll
    for (int off = 1; off < 64; off <<= 1) {
        mn = fminf(mn, __shfl_xor(mn, off));
        mx = fmaxf(mx, __shfl_xor(mx, off));
    }
    if ((threadIdx.x & 63) == 0) {
        int wid = gid >> 6;   // 0..255; waves 0..127 x-side, 128..255 y-side
        pmn[wid] = mn;
        pmx[wid] = mx;
    }

    // scaled raw vector + (q,s)
    float sc = isx ? (-1.f / 8.f) : (CCONST / 16.f);
    float o[16];
#pragma unroll
    for (int k = 0; k < 16; k++) o[k] = f[k] * sc;
    float4* dv = (float4*)((isx ? fxs : fyn) + (size_t)i * 16);
    dv[0] = make_float4(o[0], o[1], o[2], o[3]);
    dv[1] = make_float4(o[4], o[5], o[6], o[7]);
    dv[2] = make_float4(o[8], o[9], o[10], o[11]);
    dv[3] = make_float4(o[12], o[13], o[14], o[15]);
    (isx ? qsx : qsy)[i] = make_float2(q * CC256, s * CC256);

    if (isx) {
        // NCF MLP: z = [ncf_user_emb[u], ncf_item_emb[v]] (16)
        const float4* up = (const float4*)(nue + (size_t)iu * 8);
        float4 u0 = up[0], u1 = up[1];
        const float4* ip = (const float4*)(nie + (size_t)iv * 8);
        float4 i0 = ip[0], i1 = ip[1];
        float z[16];
        z[0] = u0.x; z[1] = u0.y; z[2] = u0.z; z[3] = u0.w;
        z[4] = u1.x; z[5] = u1.y; z[6] = u1.z; z[7] = u1.w;
        z[8] = i0.x; z[9] = i0.y; z[10] = i0.z; z[11] = i0.w;
        z[12] = i1.x; z[13] = i1.y; z[14] = i1.z; z[15] = i1.w;

        float p = 0.f;
#pragma unroll
        for (int k = 0; k < 8; k++) {
            float h = l1b[k];
#pragma unroll
            for (int m = 0; m < 16; m++) h = fmaf(z[m], l1w[k * 16 + m], h);
            h = fmaxf(h, 0.f);
            p = fmaf(h, l2w[k], p);
        }
        pred[i] = p;

        // MF dot: sum(mf_user_emb[u] * mf_item_emb[v])
        const float4* ap = (const float4*)(mfu + (size_t)iu * 8);
        float4 a0 = ap[0], a1 = ap[1];
        const float4* bp = (const float4*)(mfi + (size_t)iv * 8);
        float4 b0 = bp[0], b1 = bp[1];
        float wv = a0.x * b0.x + a0.y * b0.y + a0.z * b0.z + a0.w * b0.w
                 + a1.x * b1.x + a1.y * b1.y + a1.z * b1.z + a1.w * b1.w;
        wout[i] = wv;
    }
}

// Fused delta-reduce + kernel matrix. Round-7 tile shape (32 rows x 1024
// cols, grid 8x256 = 2048 blocks) restored; delta algebra from round 8.
// K[i][j] = exp2(-sqrt(max(nyc[i] + nxc[j] + dot(ay_i, ax_j), 0)))
//   nyc = qy - 2d*sy + 8*CC256*d^2 ; nxc = qx + 2d*sx + 8*CC256*d^2
// K stores nontemporal: 268 MB streamed once, never re-read.
__global__ __launch_bounds__(256) void kexp_kernel(
    const float* __restrict__ fxs, const float* __restrict__ fyn,
    const float2* __restrict__ qsx, const float2* __restrict__ qsy,
    const float* __restrict__ pmn, const float* __restrict__ pmx,
    float* __restrict__ K)
{
    __shared__ float sfy[512];
    __shared__ float sny[32];
    __shared__ float sred[4];
    int tid = threadIdx.x;
    int ib = blockIdx.y * 32;
    int jb = blockIdx.x * 1024;

    // phase 1: reduce partials; wave0:xmin wave1:xmax wave2:ymin wave3:ymax
    {
        int wv = tid >> 6, ln = tid & 63;
        const float* psrc = (wv & 1) ? pmx : pmn;
        int base = (wv >> 1) * 128;
        float u0 = psrc[base + ln], u1 = psrc[base + ln + 64];
        float v = (wv & 1) ? fmaxf(u0, u1) : fminf(u0, u1);
#pragma unroll
        for (int off = 1; off < 64; off <<= 1) {
            float o = __shfl_xor(v, off);
            v = (wv & 1) ? fmaxf(v, o) : fminf(v, o);
        }
        if (ln == 0) sred[wv] = v;
    }
    __syncthreads();
    float cx = sred[0] / (sred[1] - sred[0]);
    float cy = sred[2] / (sred[3] - sred[2]);
    float dl = cy - cx;
    float e8 = 8.f * CC256 * dl * dl;
    float dl2 = 2.f * dl;

    // phase 2: stage ay rows + corrected row norms
    for (int t = tid; t < 512; t += 256) sfy[t] = fyn[(size_t)ib * 16 + t];
    if (tid < 32) {
        float2 qs = qsy[ib + tid];
        sny[tid] = qs.x - dl2 * qs.y + e8;
    }

    // phase 3: ax cols -> regs, corrected col norms
    int j0 = jb + tid * 4;
    v2f a[4][8];
    float nxr[4];
#pragma unroll
    for (int c2 = 0; c2 < 4; c2++) {
        const float4* p = (const float4*)(fxs + (size_t)(j0 + c2) * 16);
        float4 v0 = p[0], v1 = p[1], v2 = p[2], v3 = p[3];
        a[c2][0] = (v2f){v0.x, v0.y}; a[c2][1] = (v2f){v0.z, v0.w};
        a[c2][2] = (v2f){v1.x, v1.y}; a[c2][3] = (v2f){v1.z, v1.w};
        a[c2][4] = (v2f){v2.x, v2.y}; a[c2][5] = (v2f){v2.z, v2.w};
        a[c2][6] = (v2f){v3.x, v3.y}; a[c2][7] = (v2f){v3.z, v3.w};
        float2 qs = qsx[j0 + c2];
        nxr[c2] = qs.x + dl2 * qs.y + e8;
    }
    __syncthreads();

    const float4* sfy4 = (const float4*)sfy;

#pragma unroll 2
    for (int i = 0; i < 32; i++) {
        float4 q0 = sfy4[i * 4 + 0], q1 = sfy4[i * 4 + 1];
        float4 q2 = sfy4[i * 4 + 2], q3 = sfy4[i * 4 + 3];
        v2f fy[8];
        fy[0] = (v2f){q0.x, q0.y}; fy[1] = (v2f){q0.z, q0.w};
        fy[2] = (v2f){q1.x, q1.y}; fy[3] = (v2f){q1.z, q1.w};
        fy[4] = (v2f){q2.x, q2.y}; fy[5] = (v2f){q2.z, q2.w};
        fy[6] = (v2f){q3.x, q3.y}; fy[7] = (v2f){q3.z, q3.w};
        float nyv = sny[i];
        float r[4];
#pragma unroll
        for (int c2 = 0; c2 < 4; c2++) {
            v2f acc = (v2f){nyv, nxr[c2]};
#pragma unroll
            for (int k = 0; k < 8; k++)
                acc = __builtin_elementwise_fma(a[c2][k], fy[k], acc);
            float d2 = fmaxf(acc.x + acc.y, 0.f);
            r[c2] = __builtin_amdgcn_exp2f(-__builtin_amdgcn_sqrtf(d2));
        }
        v4f o = (v4f){r[0], r[1], r[2], r[3]};
        __builtin_nontemporal_store(o, (v4f*)(K + (size_t)(ib + i) * NN + j0));
    }
}

extern "C" void kernel_launch(void* const* d_in, const int* in_sizes, int n_in,
                              void* d_out, int out_size, void* d_ws, size_t ws_size,
                              hipStream_t stream) {
    const int* x = (const int*)d_in[0];
    const int* y = (const int*)d_in[1];
    const float* W = (const float*)d_in[2];
    const float* H = (const float*)d_in[3];
    const float* nue = (const float*)d_in[4];
    const float* nie = (const float*)d_in[5];
    const float* l1w = (const float*)d_in[6];
    const float* l1b = (const float*)d_in[7];
    const float* l2w = (const float*)d_in[8];
    const float* mfu = (const float*)d_in[9];
    const float* mfi = (const float*)d_in[10];

    float* out = (float*)d_out;
    float* K = out;
    float* pred = out + (size_t)NN * NN;
    float* wout = pred + NN;

    float* pmn  = (float*)d_ws;           // 256 wave-partial mins
    float* pmx  = pmn + 256;              // 256 wave-partial maxs
    float* fxs  = pmx + 256;              // 8192 x 16 scaled x vectors
    float* fyn  = fxs + (size_t)NN * 16;  // 8192 x 16 scaled y vectors
    float2* qsx = (float2*)(fyn + (size_t)NN * 16);  // (q,s) per x col
    float2* qsy = qsx + NN;                          // (q,s) per y row

    hipLaunchKernelGGL(prep_kernel, dim3(64), dim3(256), 0, stream,
                       x, y, W, H, nue, nie, l1w, l1b, l2w, mfu, mfi, pred, wout,
                       pmn, pmx, fxs, fyn, qsx, qsy);
    hipLaunchKernelGGL(kexp_kernel, dim3(8, 256), dim3(256), 0, stream,
                       fxs, fyn, qsx, qsy, pmn, pmx, K);
}